// Round 15
// baseline (378.733 us; speedup 1.0000x reference)
//
#include <hip/hip_runtime.h>
#include <stdint.h>

#define EFFECT_DIM 758
#define ADD_DIM 10
#define EMBED_DIM 768
#define NCOLS 95000
#define NSYN 8
#define NROWS 1024
#define NT256 372            // ceil(95000/256)
#define TILE_B 32768         // 256x64 bf16 tile, fragment-ordered

typedef __attribute__((ext_vector_type(8))) __bf16 bf16x8;
typedef __attribute__((ext_vector_type(16))) float f32x16;
typedef __attribute__((ext_vector_type(4))) uint32_t u32x4;

// Fragment order: tile = [kk 0..3][grp 0..7][lane 0..63] x 16B.
// frag(kk,grp) = 1KB; lane = (row&31) + (khalf8<<5); 16B = 8 consecutive k.
// ds_read_b128 on this layout: 0 bank conflicts (measured R10-R14).

static __device__ __forceinline__ uint32_t pack2(float a, float b) {
  uint32_t r;
  asm("v_cvt_pk_bf16_f32 %0, %1, %2" : "=v"(r) : "v"(a), "v"(b));
  return r;
}

#define GLOAD16(src, dst)                                                   \
  __builtin_amdgcn_global_load_lds(                                         \
      (const __attribute__((address_space(1))) uint32_t*)(src),             \
      (__attribute__((address_space(3))) uint32_t*)(dst), 16, 0, 0)

#define F4C(f, i) ((i) == 0 ? (f).x : (i) == 1 ? (f).y : (i) == 2 ? (f).z : (f).w)

// ---------------------------------------------------------------------------
// Kernel 1: VirtualEmbedding -> bf16 A tiles (4 m-tiles x 12 ks), frag order.
// (verified R9-R14)
// ---------------------------------------------------------------------------
__global__ __launch_bounds__(256) void emb_kernel(
    const int* __restrict__ ids, const float* __restrict__ W_emb,
    const float* __restrict__ padding, const int* __restrict__ syn_table,
    const int* __restrict__ syn_mask, char* __restrict__ ws)
{
  const int l = blockIdx.x;
  const int t = threadIdx.x;
  const int id = ids[l];
  int sid[NSYN];
  int msk[NSYN];
#pragma unroll
  for (int k = 0; k < NSYN; ++k) {
    sid[k] = syn_table[id * NSYN + k];
    msk[k] = syn_mask[id * NSYN + k];
  }

  double p[9] = {0, 0, 0, 0, 0, 0, 0, 0, 0};
  for (int d = t; d < EFFECT_DIM; d += 256) {
    p[0] += (double)W_emb[(size_t)id * EFFECT_DIM + d];
#pragma unroll
    for (int k = 0; k < NSYN; ++k)
      p[k + 1] += (double)W_emb[(size_t)sid[k] * EFFECT_DIM + d];
  }

  __shared__ double s_red[9][4];
  const int w = t >> 6;
#pragma unroll
  for (int k = 0; k < 9; ++k) {
    double v = p[k];
#pragma unroll
    for (int off = 32; off > 0; off >>= 1) v += __shfl_down(v, off, 64);
    if ((t & 63) == 0) s_red[k][w] = v;
  }
  __syncthreads();

  const double isum = s_red[0][0] + s_red[0][1] + s_red[0][2] + s_red[0][3];
  float coef[NSYN];
#pragma unroll
  for (int k = 0; k < NSYN; ++k) {
    double ss = s_red[k + 1][0] + s_red[k + 1][1] + s_red[k + 1][2] + s_red[k + 1][3];
    coef[k] = msk[k] ? (float)(isum / ss) : 0.0f;
  }

  const int r = l & 255;
  char* wbase = ws + (size_t)(l >> 8) * (12 * TILE_B);

  for (int j = t; j < 384; j += 256) {
    const int d0 = 2 * j;
    float v0, v1;
    if (d0 < EFFECT_DIM) {
      const float* bp = W_emb + (size_t)id * EFFECT_DIM + d0;
      v0 = bp[0];
      v1 = bp[1];
#pragma unroll
      for (int k = 0; k < NSYN; ++k) {
        const float* sp = W_emb + (size_t)sid[k] * EFFECT_DIM + d0;
        v0 = fmaf(coef[k], sp[0], v0);
        v1 = fmaf(coef[k], sp[1], v1);
      }
    } else {
      v0 = padding[l * ADD_DIM + (d0 - EFFECT_DIM)];
      v1 = padding[l * ADD_DIM + (d0 + 1 - EFFECT_DIM)];
    }
    const int ks   = j >> 5;
    const int jl   = j & 31;
    const int kk   = jl >> 3;
    const int byte = (jl & 7) * 4;
    const int lane = (r & 31) + ((byte >> 4) << 5);
    *(uint32_t*)(wbase + ks * TILE_B + kk * 8192 + (r >> 5) * 1024 +
                 lane * 16 + (byte & 15)) = pack2(v0, v1);
  }
}

// ---------------------------------------------------------------------------
// Kernel 1b: W_rev f32 -> bf16 B tiles (372 n-tiles x 12 ks), frag order.
// (verified R9/R13)
// ---------------------------------------------------------------------------
__global__ __launch_bounds__(256) void conv_kernel(
    const float* __restrict__ Wrev, char* __restrict__ Bbuf)
{
  __shared__ char lds[16384];
  const int t   = threadIdx.x;
  const int j   = blockIdx.x;          // 0..743 (128-col half-tiles)
  const int ks  = blockIdx.y;
  const int nl4 = t & 31;
  const int kc  = t >> 5;              // 0..7: 8-k group
  const int gn4 = j * 128 + nl4 * 4;
  const bool valid = (gn4 + 4) <= NCOLS;

  float4 v[8];
  const float* p = Wrev + (size_t)(ks * 64 + kc * 8) * NCOLS + gn4;
#pragma unroll
  for (int jj = 0; jj < 8; ++jj)
    v[jj] = valid ? *(const float4*)(p + (size_t)jj * NCOLS)
                  : float4{0.0f, 0.0f, 0.0f, 0.0f};

  const int kk  = kc >> 1;
  const int lh2 = kc & 1;
#pragma unroll
  for (int i = 0; i < 4; ++i) {
    const int nloc = nl4 * 4 + i;
    u32x4 u;
#pragma unroll
    for (int j2 = 0; j2 < 4; ++j2)
      u[j2] = pack2(F4C(v[2 * j2], i), F4C(v[2 * j2 + 1], i));
    const int lane = (nloc & 31) + (lh2 << 5);
    *(u32x4*)(lds + kk * 4096 + (nl4 >> 3) * 1024 + lane * 16) = u;
  }
  __syncthreads();

  char* base = Bbuf + (size_t)((j >> 1) * 12 + ks) * TILE_B + (j & 1) * 4096;
#pragma unroll
  for (int i = 0; i < 4; ++i) {
    const int idx = i * 4096 + t * 16;
    const int k2  = idx >> 12;
    const int rem = idx & 4095;
    *(u32x4*)(base + k2 * 8192 + rem) = *(const u32x4*)(lds + idx);
  }
}

// ---------------------------------------------------------------------------
// Kernel 2 (R15 = R13 with 1/4 the synchronization): 256x256 tile, 512 thr,
// 8 waves (2m x 4n), wave 128x64, acc[4][2]. LDS 128KB = 2 sets x
// [A 32K][B 32K], frag-ordered (0 conflicts).
// Per K-tile T: ONE {vmcnt(0) + s_barrier} — at that point the ONLY
// outstanding VMEM ops are tile T's 4 units (issued 1-4 phases earlier
// during T-1, so the drain waits residual latency only), and the barrier
// doubles as the WAR guard for set reuse. Then 4 phases of pure
// {6 ds_read_b128 + issue stage unit (T+1,p) + 8 MFMA (setprio)} with NO
// waits/barriers — compiler hoists next-phase ds_reads into MFMA shadow.
// Barriers 48->12, manual waits 48->12 vs R13.
// ---------------------------------------------------------------------------
__global__ __launch_bounds__(512, 2) void gemm_pre(
    const char* __restrict__ Abuf, const char* __restrict__ Bbuf,
    float* __restrict__ out)
{
  extern __shared__ char lds[];  // set s at s*65536: [A 32K][B 32K]
  const int t = threadIdx.x;
  const int l = t & 63;
  const int w = t >> 6;
  const int wm = w >> 2;       // 0..1
  const int wn = w & 3;        // 0..3

  const int wgid = blockIdx.x;            // 1488 = 8 x 186
  const int xcd  = wgid & 7;
  const int work = xcd * 186 + (wgid >> 3);
  const int mt = work & 3;
  const int nt = work >> 2;
  const int n0 = nt * 256;

  const char* asrc = Abuf + (size_t)mt * (12 * TILE_B);
  const char* bsrc = Bbuf + (size_t)nt * (12 * TILE_B);
  const int soff = t * 16;                 // linear 8KB unit copy
  const int doff = w * 1024;               // wave-uniform LDS base

#define STAGEU(s, ksi, kkk)                                                  \
  {                                                                          \
    GLOAD16(asrc + (ksi)*TILE_B + (kkk)*8192 + soff,                         \
            lds + (s)*65536 + (kkk)*8192 + doff);                            \
    GLOAD16(bsrc + (ksi)*TILE_B + (kkk)*8192 + soff,                         \
            lds + (s)*65536 + 32768 + (kkk)*8192 + doff);                    \
  }

  // prologue: all 4 units of tile 0 -> set 0
#pragma unroll
  for (int kk = 0; kk < 4; ++kk) STAGEU(0, 0, kk);

  f32x16 acc[4][2] = {};

  for (int T = 0; T < 12; ++T) {
    const int cs = T & 1;
    const char* aw = lds + cs * 65536 + (wm * 4) * 1024 + l * 16;
    const char* bw = lds + cs * 65536 + 32768 + (wn * 2) * 1024 + l * 16;
    const bool pf = (T < 11);

    // tile boundary: outstanding == tile T's 4 units -> residual-latency
    // drain; barrier also guards set reuse (WAR).
    __builtin_amdgcn_sched_barrier(0);
    asm volatile("s_waitcnt vmcnt(0)" ::: "memory");
    __builtin_amdgcn_s_barrier();
    __builtin_amdgcn_sched_barrier(0);

#pragma unroll
    for (int p = 0; p < 4; ++p) {
      bf16x8 a[4], b[2];
#pragma unroll
      for (int mr = 0; mr < 4; ++mr)
        a[mr] = *(const bf16x8*)(aw + p * 8192 + mr * 1024);
#pragma unroll
      for (int nr = 0; nr < 2; ++nr)
        b[nr] = *(const bf16x8*)(bw + p * 8192 + nr * 1024);

      if (pf) STAGEU(cs ^ 1, T + 1, p);   // issue under MFMA shadow

      __builtin_amdgcn_s_setprio(1);
#pragma unroll
      for (int mr = 0; mr < 4; ++mr)
#pragma unroll
        for (int nr = 0; nr < 2; ++nr)
          acc[mr][nr] = __builtin_amdgcn_mfma_f32_32x32x16_bf16(
              a[mr], b[nr], acc[mr][nr], 0, 0, 0);
      __builtin_amdgcn_s_setprio(0);
    }
  }
#undef STAGEU

  // epilogue: C layout col=lane&31, row=(reg&3)+8*(reg>>2)+4*(lane>>5)
  const int lh = l >> 5;
#pragma unroll
  for (int nr = 0; nr < 2; ++nr) {
    const int gc = n0 + wn * 64 + nr * 32 + (l & 31);
    if (gc < NCOLS) {
#pragma unroll
      for (int mr = 0; mr < 4; ++mr)
#pragma unroll
        for (int reg = 0; reg < 16; ++reg) {
          const int row = mt * 256 + wm * 128 + mr * 32 +
                          (reg & 3) + 8 * (reg >> 2) + 4 * lh;
          out[(size_t)row * NCOLS + gc] = acc[mr][nr][reg];
        }
    }
  }
}

extern "C" void kernel_launch(void* const* d_in, const int* in_sizes, int n_in,
                              void* d_out, int out_size, void* d_ws, size_t ws_size,
                              hipStream_t stream) {
  const int*   ids       = (const int*)d_in[0];
  const float* W_emb     = (const float*)d_in[1];
  const float* W_rev     = (const float*)d_in[2];
  const float* padding   = (const float*)d_in[3];
  const int*   syn_table = (const int*)d_in[4];
  const int*   syn_mask  = (const int*)d_in[5];
  float* out = (float*)d_out;
  char*  ws  = (char*)d_ws;

  const size_t A_BYTES = (size_t)4 * 12 * TILE_B;        // 1.5 MB

  hipLaunchKernelGGL(emb_kernel, dim3(NROWS), dim3(256), 0, stream,
                     ids, W_emb, padding, syn_table, syn_mask, ws);

  char* Bbuf = ws + A_BYTES;
  hipLaunchKernelGGL(conv_kernel, dim3(NT256 * 2, 12), dim3(256), 0, stream,
                     W_rev, Bbuf);

  // 1488 blocks: 4 m-tiles x 372 n-tiles = 8 XCDs x 186 (bijective)
  hipLaunchKernelGGL(gemm_pre, dim3(4 * NT256), dim3(512), 131072, stream,
                     ws, Bbuf, out);
}

// Round 16
// 330.301 us; speedup vs baseline: 1.1466x; 1.1466x over previous
//
#include <hip/hip_runtime.h>
#include <stdint.h>

#define EFFECT_DIM 758
#define ADD_DIM 10
#define EMBED_DIM 768
#define NCOLS 95000
#define NSYN 8
#define NROWS 1024
#define NT256 372            // ceil(95000/256)
#define TILE_B 32768         // 256x64 bf16 A tile, fragment-ordered

typedef __attribute__((ext_vector_type(8))) __bf16 bf16x8;
typedef __attribute__((ext_vector_type(16))) float f32x16;
typedef __attribute__((ext_vector_type(4))) uint32_t u32x4;

// Fragment order: tile = [kk 0..3][grp 0..7][lane 0..63] x 16B.
// frag(kk,grp) = 1KB; lane = (row&31) + (khalf8<<5); 16B = 8 consecutive k.
// ds_read_b128 on this layout: 0 bank conflicts (measured R10-R15).

static __device__ __forceinline__ uint32_t pack2(float a, float b) {
  uint32_t r;
  asm("v_cvt_pk_bf16_f32 %0, %1, %2" : "=v"(r) : "v"(a), "v"(b));
  return r;
}

#define GLOAD16(src, dst)                                                   \
  __builtin_amdgcn_global_load_lds(                                         \
      (const __attribute__((address_space(1))) uint32_t*)(src),             \
      (__attribute__((address_space(3))) uint32_t*)(dst), 16, 0, 0)

// ---------------------------------------------------------------------------
// Kernel 1: VirtualEmbedding -> bf16 A tiles (4 m-tiles x 12 ks), frag order.
// (verified R9-R15)
// ---------------------------------------------------------------------------
__global__ __launch_bounds__(256) void emb_kernel(
    const int* __restrict__ ids, const float* __restrict__ W_emb,
    const float* __restrict__ padding, const int* __restrict__ syn_table,
    const int* __restrict__ syn_mask, char* __restrict__ ws)
{
  const int l = blockIdx.x;
  const int t = threadIdx.x;
  const int id = ids[l];
  int sid[NSYN];
  int msk[NSYN];
#pragma unroll
  for (int k = 0; k < NSYN; ++k) {
    sid[k] = syn_table[id * NSYN + k];
    msk[k] = syn_mask[id * NSYN + k];
  }

  double p[9] = {0, 0, 0, 0, 0, 0, 0, 0, 0};
  for (int d = t; d < EFFECT_DIM; d += 256) {
    p[0] += (double)W_emb[(size_t)id * EFFECT_DIM + d];
#pragma unroll
    for (int k = 0; k < NSYN; ++k)
      p[k + 1] += (double)W_emb[(size_t)sid[k] * EFFECT_DIM + d];
  }

  __shared__ double s_red[9][4];
  const int w = t >> 6;
#pragma unroll
  for (int k = 0; k < 9; ++k) {
    double v = p[k];
#pragma unroll
    for (int off = 32; off > 0; off >>= 1) v += __shfl_down(v, off, 64);
    if ((t & 63) == 0) s_red[k][w] = v;
  }
  __syncthreads();

  const double isum = s_red[0][0] + s_red[0][1] + s_red[0][2] + s_red[0][3];
  float coef[NSYN];
#pragma unroll
  for (int k = 0; k < NSYN; ++k) {
    double ss = s_red[k + 1][0] + s_red[k + 1][1] + s_red[k + 1][2] + s_red[k + 1][3];
    coef[k] = msk[k] ? (float)(isum / ss) : 0.0f;
  }

  const int r = l & 255;
  char* wbase = ws + (size_t)(l >> 8) * (12 * TILE_B);

  for (int j = t; j < 384; j += 256) {
    const int d0 = 2 * j;
    float v0, v1;
    if (d0 < EFFECT_DIM) {
      const float* bp = W_emb + (size_t)id * EFFECT_DIM + d0;
      v0 = bp[0];
      v1 = bp[1];
#pragma unroll
      for (int k = 0; k < NSYN; ++k) {
        const float* sp = W_emb + (size_t)sid[k] * EFFECT_DIM + d0;
        v0 = fmaf(coef[k], sp[0], v0);
        v1 = fmaf(coef[k], sp[1], v1);
      }
    } else {
      v0 = padding[l * ADD_DIM + (d0 - EFFECT_DIM)];
      v1 = padding[l * ADD_DIM + (d0 + 1 - EFFECT_DIM)];
    }
    const int ks   = j >> 5;
    const int jl   = j & 31;
    const int kk   = jl >> 3;
    const int byte = (jl & 7) * 4;
    const int lane = (r & 31) + ((byte >> 4) << 5);
    *(uint32_t*)(wbase + ks * TILE_B + kk * 8192 + (r >> 5) * 1024 +
                 lane * 16 + (byte & 15)) = pack2(v0, v1);
  }
}

// ---------------------------------------------------------------------------
// Kernel 2 (R16 = R14 fused + 2-deep B pipeline): 256x256 tile, 512 thr,
// 8 waves (2m x 4n), wave 128x64, acc[4][2]. LDS 128KB = 2 sets x
// [A 32K][B 32K], frag-ordered. Per K-step T (computing set cs = T&1):
//   AGLD(cs^1, T+1)            // 4 gload_lds, OLDEST in vm queue
//   BLOAD(brNext, T+2)         // 32 f32, stay in flight 2 steps
//   4 x {6 ds_read_b128 + 8 MFMA (setprio)}   // no waits inside
//   BSTORE(brCur = B(T+1))     // loaded a FULL step ago -> retired, no stall
//   lgkmcnt(0); vmcnt(32)      // A(T+1) confirmed (older), B(T+2) in flight
//   s_barrier
// 12 barriers, 12 counted waits. Conv pass deleted. T1 remap 1488 = 8x186:
// 4 mt-siblings share each W_rev panel on one XCD (f32 B read ~once).
// ---------------------------------------------------------------------------
__global__ __launch_bounds__(512, 2) void gemm_fused(
    const float* __restrict__ Wrev, const char* __restrict__ Abuf,
    float* __restrict__ out)
{
  extern __shared__ char lds[];  // set s at s*65536: [A 32K][B 32K]
  const int t = threadIdx.x;
  const int l = t & 63;
  const int w = t >> 6;
  const int wm = w >> 2;       // 0..1
  const int wn = w & 3;        // 0..3

  const int wgid = blockIdx.x;            // 1488 = 8 x 186
  const int xcd  = wgid & 7;
  const int work = xcd * 186 + (wgid >> 3);
  const int mt = work & 3;
  const int nt = work >> 2;
  const int n0 = nt * 256;

  const char* asrc = Abuf + (size_t)mt * (12 * TILE_B);

  // B staging role: thread owns col sn (0..255), k-rows kg*32..+31
  const int sn = t & 255;
  const int kg = t >> 8;       // 0..1
  const int gn = n0 + sn;
  const bool valid = gn < NCOLS;

  float br0[32], br1[32];

#define AGLD(s, ksi)                                                         \
  {                                                                          \
    _Pragma("unroll") for (int kk = 0; kk < 4; ++kk)                         \
      GLOAD16(asrc + (ksi)*TILE_B + kk*8192 + t*16,                          \
              lds + (s)*65536 + kk*8192 + w*1024);                           \
  }

#define BLOAD(br, ksi)                                                       \
  {                                                                          \
    const float* p = Wrev + (size_t)((ksi)*64 + kg*32) * NCOLS + gn;         \
    _Pragma("unroll") for (int j = 0; j < 32; ++j)                           \
      br[j] = valid ? p[(size_t)j * NCOLS] : 0.0f;                           \
  }

#define BSTORE(br, s)                                                        \
  {                                                                          \
    _Pragma("unroll") for (int c = 0; c < 2; ++c) {                          \
      u32x4 u0, u1;                                                          \
      _Pragma("unroll") for (int j = 0; j < 4; ++j) {                        \
        u0[j] = pack2(br[c*16 + 2*j],     br[c*16 + 2*j + 1]);               \
        u1[j] = pack2(br[c*16 + 8 + 2*j], br[c*16 + 9 + 2*j]);               \
      }                                                                      \
      char* bb = lds + (s)*65536 + 32768 + (kg*2 + c)*8192 + (sn>>5)*1024;   \
      *(u32x4*)(bb + (sn & 31)*16) = u0;                                     \
      *(u32x4*)(bb + ((sn & 31) + 32)*16) = u1;                              \
    }                                                                        \
  }

#define COMPUTE(cs)                                                          \
  {                                                                          \
    const char* aw = lds + (cs)*65536 + (wm*4)*1024 + l*16;                  \
    const char* bw = lds + (cs)*65536 + 32768 + (wn*2)*1024 + l*16;          \
    _Pragma("unroll") for (int p = 0; p < 4; ++p) {                          \
      bf16x8 a[4], b[2];                                                     \
      _Pragma("unroll") for (int mr = 0; mr < 4; ++mr)                       \
        a[mr] = *(const bf16x8*)(aw + p*8192 + mr*1024);                     \
      _Pragma("unroll") for (int nr = 0; nr < 2; ++nr)                       \
        b[nr] = *(const bf16x8*)(bw + p*8192 + nr*1024);                     \
      __builtin_amdgcn_s_setprio(1);                                         \
      _Pragma("unroll") for (int mr = 0; mr < 4; ++mr)                       \
        _Pragma("unroll") for (int nr = 0; nr < 2; ++nr)                     \
          acc[mr][nr] = __builtin_amdgcn_mfma_f32_32x32x16_bf16(             \
              a[mr], b[nr], acc[mr][nr], 0, 0, 0);                           \
      __builtin_amdgcn_s_setprio(0);                                         \
    }                                                                        \
  }

  // one full pipelined step: compute set cs / tile TT; prep set cs^1
#define STEP(cs, TT, brCur, brNext)                                          \
  {                                                                          \
    if ((TT) + 1 < 12) AGLD((cs) ^ 1, (TT) + 1);       /* oldest in queue */ \
    if ((TT) + 2 < 12) BLOAD(brNext, (TT) + 2);                              \
    __builtin_amdgcn_sched_barrier(0);                                       \
    COMPUTE(cs);                                                             \
    __builtin_amdgcn_sched_barrier(0);                                       \
    if ((TT) + 1 < 12) {                                                     \
      BSTORE(brCur, (cs) ^ 1);         /* brCur loaded a full step ago */    \
      asm volatile("s_waitcnt lgkmcnt(0)" ::: "memory");                     \
      if ((TT) + 2 < 12) asm volatile("s_waitcnt vmcnt(32)" ::: "memory");   \
      else               asm volatile("s_waitcnt vmcnt(0)" ::: "memory");    \
      __builtin_amdgcn_sched_barrier(0);                                     \
      __builtin_amdgcn_s_barrier();                                          \
    }                                                                        \
  }

  // prologue: tile 0 -> set 0; preload B(1) into br0
  AGLD(0, 0);
  BLOAD(br0, 0);
  BSTORE(br0, 0);   // compiler waits br0 (drains A(0) too — older)
  BLOAD(br0, 1);
  asm volatile("s_waitcnt lgkmcnt(0)" ::: "memory");
  __builtin_amdgcn_sched_barrier(0);
  __builtin_amdgcn_s_barrier();

  f32x16 acc[4][2] = {};

#pragma unroll
  for (int Ti = 0; Ti < 6; ++Ti) {
    STEP(0, 2 * Ti,     br0, br1);
    STEP(1, 2 * Ti + 1, br1, br0);
  }
#undef STEP
#undef COMPUTE
#undef AGLD
#undef BLOAD
#undef BSTORE

  // epilogue: C layout col=lane&31, row=(reg&3)+8*(reg>>2)+4*(lane>>5)
  const int lh = l >> 5;
#pragma unroll
  for (int nr = 0; nr < 2; ++nr) {
    const int gc = n0 + wn * 64 + nr * 32 + (l & 31);
    if (gc < NCOLS) {
#pragma unroll
      for (int mr = 0; mr < 4; ++mr)
#pragma unroll
        for (int reg = 0; reg < 16; ++reg) {
          const int row = mt * 256 + wm * 128 + mr * 32 +
                          (reg & 3) + 8 * (reg >> 2) + 4 * lh;
          out[(size_t)row * NCOLS + gc] = acc[mr][nr][reg];
        }
    }
  }
}

extern "C" void kernel_launch(void* const* d_in, const int* in_sizes, int n_in,
                              void* d_out, int out_size, void* d_ws, size_t ws_size,
                              hipStream_t stream) {
  const int*   ids       = (const int*)d_in[0];
  const float* W_emb     = (const float*)d_in[1];
  const float* W_rev     = (const float*)d_in[2];
  const float* padding   = (const float*)d_in[3];
  const int*   syn_table = (const int*)d_in[4];
  const int*   syn_mask  = (const int*)d_in[5];
  float* out = (float*)d_out;
  char*  ws  = (char*)d_ws;

  // A tiles in ws[0, 1.5MB); conv pass deleted
  hipLaunchKernelGGL(emb_kernel, dim3(NROWS), dim3(256), 0, stream,
                     ids, W_emb, padding, syn_table, syn_mask, ws);

  // 1488 blocks: 4 m-tiles x 372 n-tiles = 8 XCDs x 186 (bijective)
  hipLaunchKernelGGL(gemm_fused, dim3(4 * NT256), dim3(512), 131072, stream,
                     W_rev, ws, out);
}